// Round 1
// baseline (221.610 us; speedup 1.0000x reference)
//
#include <hip/hip_runtime.h>
#include <stdint.h>

#define AQ_MAX 15.0f
#define BN_EPS 1e-5f

// ---------------------------------------------------------------------------
// Prep: per-output-channel int4 symmetric fake-quant of weights + BN fold.
// One block per output channel, 64 threads (1 wave). K <= 48.
// ---------------------------------------------------------------------------
__global__ __launch_bounds__(64) void prep_kernel(
    const float* __restrict__ w,
    const float* __restrict__ g, const float* __restrict__ b,
    const float* __restrict__ m, const float* __restrict__ v,
    float* __restrict__ wq, float* __restrict__ inv, float* __restrict__ beta,
    int K) {
  int c = blockIdx.x, t = threadIdx.x;
  const float* wc = w + (size_t)c * K;
  float a = (t < K) ? fabsf(wc[t]) : 0.0f;
#pragma unroll
  for (int off = 32; off >= 1; off >>= 1) a = fmaxf(a, __shfl_xor(a, off));
  float s = fmaxf(a / 7.0f, 1e-8f);
  if (t < K) {
    float q = rintf(wc[t] / s);            // round half-to-even, same as jnp.round
    q = fminf(7.0f, fmaxf(-7.0f, q));
    wq[(size_t)c * K + t] = q * s;
  }
  if (t == 0) {
    float iv = g[c] / sqrtf(v[c] + BN_EPS);
    inv[c] = iv;
    beta[c] = b[c] - m[c] * iv;
  }
}

// ---------------------------------------------------------------------------
// Stage 1: conv 3x3 stride2 pad0, 3->32, input fp32 [8,3,512,1024],
// output uint4 codes [8,32,255,511]. One thread per output pixel (all 32 oc).
// ---------------------------------------------------------------------------
__global__ __launch_bounds__(256) void stage1_kernel(
    const float* __restrict__ x, const float* __restrict__ P,
    const float* __restrict__ s1p, uint8_t* __restrict__ out) {
  __shared__ float sw[864];
  __shared__ float sinv[32], sbeta[32];
  for (int i = threadIdx.x; i < 864; i += 256) sw[i] = P[i];
  if (threadIdx.x < 32) {
    sinv[threadIdx.x] = P[6192 + threadIdx.x];
    sbeta[threadIdx.x] = P[6224 + threadIdx.x];
  }
  __syncthreads();
  int tid = blockIdx.x * 256 + threadIdx.x;
  const int total = 8 * 255 * 511;
  if (tid >= total) return;
  float s1 = *s1p;
  int ox = tid % 511;
  int t2 = tid / 511;
  int oy = t2 % 255;
  int n  = t2 / 255;
  int iy = 2 * oy, ix = 2 * ox;
  float r[27];
#pragma unroll
  for (int ic = 0; ic < 3; ic++)
#pragma unroll
    for (int kh = 0; kh < 3; kh++)
#pragma unroll
      for (int kw = 0; kw < 3; kw++)
        r[ic * 9 + kh * 3 + kw] =
            x[(((size_t)n * 3 + ic) * 512 + (iy + kh)) * 1024 + (ix + kw)];
  size_t obase = (((size_t)n * 32) * 255 + oy) * 511 + ox;
#pragma unroll 4
  for (int oc = 0; oc < 32; oc++) {
    float acc = 0.0f;
#pragma unroll
    for (int j = 0; j < 27; j++) acc = fmaf(r[j], sw[oc * 27 + j], acc);
    float y = fmaf(acc, sinv[oc], sbeta[oc]);
    float q = rintf(y / s1);
    q = fminf(AQ_MAX, fmaxf(0.0f, q));
    out[obase + (size_t)oc * (255 * 511)] = (uint8_t)q;
  }
}

// ---------------------------------------------------------------------------
// Depthwise 3x3 stride2 pad1. Input/output uint4 codes. One thread/output.
// ---------------------------------------------------------------------------
__global__ __launch_bounds__(256) void dw_kernel(
    const uint8_t* __restrict__ in, const float* __restrict__ wq,
    const float* __restrict__ inv, const float* __restrict__ beta,
    const float* __restrict__ sin_p, const float* __restrict__ sout_p,
    uint8_t* __restrict__ out, int C, int IH, int IW, int OH, int OW) {
  int tid = blockIdx.x * 256 + threadIdx.x;
  int total = 8 * C * OH * OW;
  if (tid >= total) return;
  float s_in = *sin_p, s_out = *sout_p;
  int ox = tid % OW;
  int t2 = tid / OW;
  int oy = t2 % OH;
  int t3 = t2 / OH;
  int c = t3 % C;
  int n = t3 / C;
  const uint8_t* ip = in + ((size_t)n * C + c) * IH * IW;
  const float* wc = wq + c * 9;
  float acc = 0.0f;
#pragma unroll
  for (int kh = 0; kh < 3; kh++) {
    int iy = 2 * oy + kh - 1;
    if (iy < 0 || iy >= IH) continue;
#pragma unroll
    for (int kw = 0; kw < 3; kw++) {
      int ix = 2 * ox + kw - 1;
      if (ix < 0 || ix >= IW) continue;
      float xv = (float)ip[(size_t)iy * IW + ix] * s_in;
      acc = fmaf(xv, wc[kh * 3 + kw], acc);
    }
  }
  float y = fmaf(acc, inv[c], beta[c]);
  float q = rintf(y / s_out);
  q = fminf(AQ_MAX, fmaxf(0.0f, q));
  out[tid] = (uint8_t)q;
}

// ---------------------------------------------------------------------------
// Pointwise 1x1. One thread per pixel, computes all OC. Codes in, codes out.
// ---------------------------------------------------------------------------
template <int IC, int OC>
__global__ __launch_bounds__(256) void pw_kernel(
    const uint8_t* __restrict__ in, const float* __restrict__ wq,
    const float* __restrict__ inv, const float* __restrict__ beta,
    const float* __restrict__ sin_p, const float* __restrict__ sout_p,
    uint8_t* __restrict__ out, int H, int W) {
  __shared__ float sw[IC * OC];
  __shared__ float sinv[OC], sbeta[OC];
  for (int i = threadIdx.x; i < IC * OC; i += 256) sw[i] = wq[i];
  for (int i = threadIdx.x; i < OC; i += 256) { sinv[i] = inv[i]; sbeta[i] = beta[i]; }
  __syncthreads();
  int tid = blockIdx.x * 256 + threadIdx.x;
  int total = 8 * H * W;
  if (tid >= total) return;
  float s_in = *sin_p, s_out = *sout_p;
  int hw = H * W;
  int px = tid % hw;
  int n  = tid / hw;
  float xv[IC];
  size_t ibase = (size_t)n * IC * hw + px;
#pragma unroll
  for (int ic = 0; ic < IC; ic++) xv[ic] = (float)in[ibase + (size_t)ic * hw] * s_in;
  size_t obase = (size_t)n * OC * hw + px;
  for (int oc = 0; oc < OC; oc++) {
    float acc = 0.0f;
#pragma unroll
    for (int ic = 0; ic < IC; ic++) acc = fmaf(xv[ic], sw[oc * IC + ic], acc);
    float y = fmaf(acc, sinv[oc], sbeta[oc]);
    float q = rintf(y / s_out);
    q = fminf(AQ_MAX, fmaxf(0.0f, q));
    out[obase + (size_t)oc * hw] = (uint8_t)q;
  }
}

// Final pointwise: writes fp32 to d_out.
template <int IC, int OC>
__global__ __launch_bounds__(256) void pw_final_kernel(
    const uint8_t* __restrict__ in, const float* __restrict__ wq,
    const float* __restrict__ inv, const float* __restrict__ beta,
    const float* __restrict__ sin_p, const float* __restrict__ sout_p,
    float* __restrict__ out, int H, int W) {
  __shared__ float sw[IC * OC];
  __shared__ float sinv[OC], sbeta[OC];
  for (int i = threadIdx.x; i < IC * OC; i += 256) sw[i] = wq[i];
  for (int i = threadIdx.x; i < OC; i += 256) { sinv[i] = inv[i]; sbeta[i] = beta[i]; }
  __syncthreads();
  int tid = blockIdx.x * 256 + threadIdx.x;
  int total = 8 * H * W;
  if (tid >= total) return;
  float s_in = *sin_p, s_out = *sout_p;
  int hw = H * W;
  int px = tid % hw;
  int n  = tid / hw;
  float xv[IC];
  size_t ibase = (size_t)n * IC * hw + px;
#pragma unroll
  for (int ic = 0; ic < IC; ic++) xv[ic] = (float)in[ibase + (size_t)ic * hw] * s_in;
  size_t obase = (size_t)n * OC * hw + px;
  for (int oc = 0; oc < OC; oc++) {
    float acc = 0.0f;
#pragma unroll
    for (int ic = 0; ic < IC; ic++) acc = fmaf(xv[ic], sw[oc * IC + ic], acc);
    float y = fmaf(acc, sinv[oc], sbeta[oc]);
    float q = rintf(y / s_out);
    q = fminf(AQ_MAX, fmaxf(0.0f, q));
    out[obase + (size_t)oc * hw] = q * s_out;
  }
}

extern "C" void kernel_launch(void* const* d_in, const int* in_sizes, int n_in,
                              void* d_out, int out_size, void* d_ws, size_t ws_size,
                              hipStream_t stream) {
  const float* x    = (const float*)d_in[0];
  const float* w1   = (const float*)d_in[1];
  const float* g1   = (const float*)d_in[2];
  const float* b1   = (const float*)d_in[3];
  const float* m1   = (const float*)d_in[4];
  const float* v1   = (const float*)d_in[5];
  const float* s1   = (const float*)d_in[6];
  const float* wdw1 = (const float*)d_in[7];
  const float* g2   = (const float*)d_in[8];
  const float* b2   = (const float*)d_in[9];
  const float* m2   = (const float*)d_in[10];
  const float* v2   = (const float*)d_in[11];
  const float* s2   = (const float*)d_in[12];
  const float* wpw1 = (const float*)d_in[13];
  const float* g3   = (const float*)d_in[14];
  const float* b3   = (const float*)d_in[15];
  const float* m3   = (const float*)d_in[16];
  const float* v3   = (const float*)d_in[17];
  const float* s3   = (const float*)d_in[18];
  const float* wdw2 = (const float*)d_in[19];
  const float* g4   = (const float*)d_in[20];
  const float* b4   = (const float*)d_in[21];
  const float* m4   = (const float*)d_in[22];
  const float* v4   = (const float*)d_in[23];
  const float* s4   = (const float*)d_in[24];
  const float* wpw2 = (const float*)d_in[25];
  const float* g5   = (const float*)d_in[26];
  const float* b5   = (const float*)d_in[27];
  const float* m5   = (const float*)d_in[28];
  const float* v5   = (const float*)d_in[29];
  const float* s5   = (const float*)d_in[30];

  // Workspace layout.
  // Params (floats): wq1[864] wq2[288] wq3[1536] wq4[432] wq5[3072]
  //                  inv1/beta1[32+32] inv2/beta2 inv3/beta3[48+48] inv4/beta4 inv5/beta5[64+64]
  float* P = (float*)d_ws;
  float* wq1 = P + 0;
  float* wq2 = P + 864;
  float* wq3 = P + 1152;
  float* wq4 = P + 2688;
  float* wq5 = P + 3120;
  float* inv1 = P + 6192, *beta1 = P + 6224;
  float* inv2 = P + 6256, *beta2 = P + 6288;
  float* inv3 = P + 6320, *beta3 = P + 6368;
  float* inv4 = P + 6416, *beta4 = P + 6464;
  float* inv5 = P + 6512, *beta5 = P + 6576;

  uint8_t* ws8 = (uint8_t*)d_ws;
  uint8_t* x1 = ws8 + 32768;                 // [8,32,255,511] codes: 33,358,080 B
  uint8_t* x2 = x1 + 33358080;               // [8,32,128,256]:  8,388,608 B
  uint8_t* x3 = x2 + 8388608;                // [8,48,128,256]: 12,582,912 B
  uint8_t* x4 = x3 + 12582912;               // [8,48,64,128]:   3,145,728 B

  prep_kernel<<<32, 64, 0, stream>>>(w1,   g1, b1, m1, v1, wq1, inv1, beta1, 27);
  prep_kernel<<<32, 64, 0, stream>>>(wdw1, g2, b2, m2, v2, wq2, inv2, beta2, 9);
  prep_kernel<<<48, 64, 0, stream>>>(wpw1, g3, b3, m3, v3, wq3, inv3, beta3, 32);
  prep_kernel<<<48, 64, 0, stream>>>(wdw2, g4, b4, m4, v4, wq4, inv4, beta4, 9);
  prep_kernel<<<64, 64, 0, stream>>>(wpw2, g5, b5, m5, v5, wq5, inv5, beta5, 48);

  // Stage 1: 8*255*511 = 1,042,440 pixel-threads
  stage1_kernel<<<(1042440 + 255) / 256, 256, 0, stream>>>(x, P, s1, x1);
  // Stage 2: dw 32ch, 255x511 -> 128x256: 8,388,608 threads
  dw_kernel<<<8388608 / 256, 256, 0, stream>>>(x1, wq2, inv2, beta2, s1, s2, x2,
                                               32, 255, 511, 128, 256);
  // Stage 3: pw 32->48 @128x256: 262,144 pixel-threads
  pw_kernel<32, 48><<<262144 / 256, 256, 0, stream>>>(x2, wq3, inv3, beta3, s2, s3,
                                                      x3, 128, 256);
  // Stage 4: dw 48ch, 128x256 -> 64x128: 3,145,728 threads
  dw_kernel<<<3145728 / 256, 256, 0, stream>>>(x3, wq4, inv4, beta4, s3, s4, x4,
                                               48, 128, 256, 64, 128);
  // Stage 5: pw 48->64 @64x128 -> fp32 d_out: 65,536 pixel-threads
  pw_final_kernel<48, 64><<<65536 / 256, 256, 0, stream>>>(x4, wq5, inv5, beta5,
                                                           s4, s5, (float*)d_out,
                                                           64, 128);
}

// Round 2
// 129.280 us; speedup vs baseline: 1.7142x; 1.7142x over previous
//
#include <hip/hip_runtime.h>
#include <stdint.h>

#define AQ_MAX 15.0f
#define BN_EPS 1e-5f

// ---------------------------------------------------------------------------
// Merged prep: per-output-channel int4 symmetric weight fake-quant + BN fold.
// 224 blocks x 64 threads; block range selects which tensor/channel.
// P layout (floats): wq1[864]@0 wq2[288]@864 wq3[1536]@1152 wq4[432]@2688
//   wq5[3072]@3120 inv1@6192 beta1@6224 inv2@6256 beta2@6288 inv3@6320
//   beta3@6368 inv4@6416 beta4@6464 inv5@6512 beta5@6576 (end 6640)
// ---------------------------------------------------------------------------
__global__ __launch_bounds__(64) void prep_all(
    const float* __restrict__ wA, const float* __restrict__ gA,
    const float* __restrict__ bA, const float* __restrict__ mA,
    const float* __restrict__ vA,
    const float* __restrict__ wB, const float* __restrict__ gB,
    const float* __restrict__ bB, const float* __restrict__ mB,
    const float* __restrict__ vB,
    const float* __restrict__ wC, const float* __restrict__ gC,
    const float* __restrict__ bC, const float* __restrict__ mC,
    const float* __restrict__ vC,
    const float* __restrict__ wD, const float* __restrict__ gD,
    const float* __restrict__ bD, const float* __restrict__ mD,
    const float* __restrict__ vD,
    const float* __restrict__ wE, const float* __restrict__ gE,
    const float* __restrict__ bE, const float* __restrict__ mE,
    const float* __restrict__ vE,
    float* __restrict__ P) {
  int blk = blockIdx.x, t = threadIdx.x;
  const float *w, *g, *b, *m, *v;
  float *wq, *inv, *beta;
  int K, c;
  if (blk < 32) {
    c = blk; w = wA; g = gA; b = bA; m = mA; v = vA; K = 27;
    wq = P + 0; inv = P + 6192; beta = P + 6224;
  } else if (blk < 64) {
    c = blk - 32; w = wB; g = gB; b = bB; m = mB; v = vB; K = 9;
    wq = P + 864; inv = P + 6256; beta = P + 6288;
  } else if (blk < 112) {
    c = blk - 64; w = wC; g = gC; b = bC; m = mC; v = vC; K = 32;
    wq = P + 1152; inv = P + 6320; beta = P + 6368;
  } else if (blk < 160) {
    c = blk - 112; w = wD; g = gD; b = bD; m = mD; v = vD; K = 9;
    wq = P + 2688; inv = P + 6416; beta = P + 6464;
  } else {
    c = blk - 160; w = wE; g = gE; b = bE; m = mE; v = vE; K = 48;
    wq = P + 3120; inv = P + 6512; beta = P + 6576;
  }
  const float* wc = w + (size_t)c * K;
  float a = (t < K) ? fabsf(wc[t]) : 0.0f;
#pragma unroll
  for (int off = 32; off >= 1; off >>= 1) a = fmaxf(a, __shfl_xor(a, off));
  float s = fmaxf(a / 7.0f, 1e-8f);
  if (t < K) {
    float q = rintf(wc[t] / s);  // round half-to-even, same as jnp.round
    q = fminf(7.0f, fmaxf(-7.0f, q));
    wq[(size_t)c * K + t] = q * s;
  }
  if (t == 0) {
    float iv = g[c] / sqrtf(v[c] + BN_EPS);
    inv[c] = iv;
    beta[c] = b[c] - m[c] * iv;
  }
}

// ---------------------------------------------------------------------------
// Stage 1: conv 3x3 s2 p0, 3->32, fp32 [8,3,512,1024] -> uint4 codes
// [8,32,255,512(pad; logical 511)]. 4 output pixels per thread along ox.
// ---------------------------------------------------------------------------
__global__ __launch_bounds__(256) void stage1_kernel(
    const float* __restrict__ x, const float* __restrict__ P,
    const float* __restrict__ s1p, uint8_t* __restrict__ out) {
  __shared__ float sw[32 * 28];  // 27 weights/oc, padded to 28 for b128 reads
  __shared__ float sinv[32], sbeta[32];
  for (int i = threadIdx.x; i < 32 * 28; i += 256) {
    int oc = i / 28, j = i % 28;
    sw[i] = (j < 27) ? P[oc * 27 + j] : 0.0f;
  }
  if (threadIdx.x < 32) {
    sinv[threadIdx.x] = P[6192 + threadIdx.x];
    sbeta[threadIdx.x] = P[6224 + threadIdx.x];
  }
  __syncthreads();
  int tid = blockIdx.x * 256 + threadIdx.x;  // 8*255*128 = 261120 threads
  int gx = tid & 127;
  int t2 = tid >> 7;
  int oy = t2 % 255;
  int n = t2 / 255;
  float s1 = *s1p;
  int ix0 = gx * 8, iy = 2 * oy;
  float r[9][9];
#pragma unroll
  for (int ic = 0; ic < 3; ic++)
#pragma unroll
    for (int kh = 0; kh < 3; kh++) {
      const float* bp = x + (((size_t)(n * 3 + ic)) * 512 + (iy + kh)) * 1024 + ix0;
      float4 f0 = *(const float4*)bp;
      float4 f1 = *(const float4*)(bp + 4);
      float f8 = bp[8];
      int s = ic * 3 + kh;
      r[s][0] = f0.x; r[s][1] = f0.y; r[s][2] = f0.z; r[s][3] = f0.w;
      r[s][4] = f1.x; r[s][5] = f1.y; r[s][6] = f1.z; r[s][7] = f1.w;
      r[s][8] = f8;
    }
  size_t obase = (((size_t)n * 32) * 255 + oy) * 512 + gx * 4;
#pragma unroll 2
  for (int oc = 0; oc < 32; oc++) {
    float w[28];
#pragma unroll
    for (int t = 0; t < 7; t++) {
      float4 f = *(const float4*)&sw[oc * 28 + 4 * t];
      w[4 * t] = f.x; w[4 * t + 1] = f.y; w[4 * t + 2] = f.z; w[4 * t + 3] = f.w;
    }
    float acc0 = 0, acc1 = 0, acc2 = 0, acc3 = 0;
#pragma unroll
    for (int s = 0; s < 9; s++) {
#pragma unroll
      for (int kw = 0; kw < 3; kw++) {
        float wv = w[s * 3 + kw];
        acc0 = fmaf(r[s][0 + kw], wv, acc0);
        acc1 = fmaf(r[s][2 + kw], wv, acc1);
        acc2 = fmaf(r[s][4 + kw], wv, acc2);
        acc3 = fmaf(r[s][6 + kw], wv, acc3);
      }
    }
    float iv = sinv[oc], bt = sbeta[oc];
    float y0 = fmaf(acc0, iv, bt), y1 = fmaf(acc1, iv, bt);
    float y2 = fmaf(acc2, iv, bt), y3 = fmaf(acc3, iv, bt);
    uint32_t q0 = (uint32_t)fminf(AQ_MAX, fmaxf(0.0f, rintf(y0 / s1)));
    uint32_t q1 = (uint32_t)fminf(AQ_MAX, fmaxf(0.0f, rintf(y1 / s1)));
    uint32_t q2 = (uint32_t)fminf(AQ_MAX, fmaxf(0.0f, rintf(y2 / s1)));
    uint32_t q3 = (uint32_t)fminf(AQ_MAX, fmaxf(0.0f, rintf(y3 / s1)));
    *(uint32_t*)(out + obase + (size_t)oc * (255 * 512)) =
        q0 | (q1 << 8) | (q2 << 16) | (q3 << 24);
  }
}

// ---------------------------------------------------------------------------
// Depthwise 3x3 s2 p1, codes in -> codes out. 4 output pixels per thread.
// IWL = logical input width (mask >=IWL as pad), IWP = physical row stride.
// ---------------------------------------------------------------------------
template <int C, int IH, int IWL, int IWP, int OH, int OW>
__global__ __launch_bounds__(256) void dw_kernel(
    const uint8_t* __restrict__ in, const float* __restrict__ wq,
    const float* __restrict__ inv, const float* __restrict__ beta,
    const float* __restrict__ sin_p, const float* __restrict__ sout_p,
    uint8_t* __restrict__ out) {
  constexpr int GX = OW / 4;
  int tid = blockIdx.x * 256 + threadIdx.x;
  int oxg = tid % GX;
  int t2 = tid / GX;
  int oy = t2 % OH;
  int t3 = t2 / OH;
  int c = t3 % C;
  int n = t3 / C;
  float s_in = *sin_p, s_out = *sout_p;
  const float* wc = wq + c * 9;
  float w[9];
#pragma unroll
  for (int j = 0; j < 9; j++) w[j] = wc[j];
  float iv = inv[c], bt = beta[c];
  int c0 = oxg * 8;
  const uint8_t* chan = in + ((size_t)(n * C + c)) * IH * IWP;
  float xr[3][9];
#pragma unroll
  for (int kh = 0; kh < 3; kh++) {
    int iy = 2 * oy + kh - 1;
    if (iy >= 0 && iy < IH) {
      const uint8_t* rp = chan + (size_t)iy * IWP;
      uint2 u = *(const uint2*)(rp + c0);
      xr[kh][0] = (oxg > 0) ? (float)rp[c0 - 1] : 0.0f;
#pragma unroll
      for (int j = 0; j < 4; j++) xr[kh][1 + j] = (float)((u.x >> (8 * j)) & 255u);
#pragma unroll
      for (int j = 0; j < 4; j++) xr[kh][5 + j] = (float)((u.y >> (8 * j)) & 255u);
      if (IWL < IWP && oxg == GX - 1) xr[kh][8] = 0.0f;  // pad col beyond IWL
    } else {
#pragma unroll
      for (int j = 0; j < 9; j++) xr[kh][j] = 0.0f;
    }
  }
#pragma unroll
  for (int kh = 0; kh < 3; kh++)
#pragma unroll
    for (int j = 0; j < 9; j++) xr[kh][j] *= s_in;  // dequant (exact order)
  float acc[4] = {0, 0, 0, 0};
#pragma unroll
  for (int kh = 0; kh < 3; kh++)
#pragma unroll
    for (int kw = 0; kw < 3; kw++) {
      float wv = w[kh * 3 + kw];
#pragma unroll
      for (int p = 0; p < 4; p++) acc[p] = fmaf(xr[kh][2 * p + kw], wv, acc[p]);
    }
  uint32_t pack = 0;
#pragma unroll
  for (int p = 0; p < 4; p++) {
    float y = fmaf(acc[p], iv, bt);
    float q = fminf(AQ_MAX, fmaxf(0.0f, rintf(y / s_out)));
    pack |= ((uint32_t)q) << (8 * p);
  }
  *(uint32_t*)(out + ((size_t)(n * C + c) * OH + oy) * OW + c0 / 2) = pack;
}

// ---------------------------------------------------------------------------
// Pointwise 1x1, codes in. 2 pixels per thread, all OC per thread.
// FINAL=true writes dequantized fp32 to d_out.
// ---------------------------------------------------------------------------
template <int IC, int OC, int HW, bool FINAL>
__global__ __launch_bounds__(256) void pw_kernel(
    const uint8_t* __restrict__ in, const float* __restrict__ Pw,
    const float* __restrict__ Pinv, const float* __restrict__ Pbeta,
    const float* __restrict__ sin_p, const float* __restrict__ sout_p,
    void* __restrict__ outv) {
  __shared__ float sw[OC * IC];
  __shared__ float sinv[OC], sbeta[OC];
  for (int i = threadIdx.x; i < OC * IC; i += 256) sw[i] = Pw[i];
  for (int i = threadIdx.x; i < OC; i += 256) {
    sinv[i] = Pinv[i]; sbeta[i] = Pbeta[i];
  }
  __syncthreads();
  int tid = blockIdx.x * 256 + threadIdx.x;
  float s_in = *sin_p, s_out = *sout_p;
  constexpr int PG = HW / 2;
  int px0 = (tid % PG) * 2;
  int n = tid / PG;
  const uint8_t* ib = in + (size_t)n * IC * HW + px0;
  float xa[IC], xb[IC];
#pragma unroll
  for (int ic = 0; ic < IC; ic++) {
    uint16_t u = *(const uint16_t*)(ib + (size_t)ic * HW);
    xa[ic] = (float)(u & 255u) * s_in;
    xb[ic] = (float)(u >> 8) * s_in;
  }
#pragma unroll 2
  for (int oc = 0; oc < OC; oc++) {
    float w[IC];
#pragma unroll
    for (int t = 0; t < IC / 4; t++) {
      float4 f = *(const float4*)&sw[oc * IC + 4 * t];
      w[4 * t] = f.x; w[4 * t + 1] = f.y; w[4 * t + 2] = f.z; w[4 * t + 3] = f.w;
    }
    float a0 = 0, a1 = 0;
#pragma unroll
    for (int ic = 0; ic < IC; ic++) {
      a0 = fmaf(xa[ic], w[ic], a0);
      a1 = fmaf(xb[ic], w[ic], a1);
    }
    float iv = sinv[oc], bt = sbeta[oc];
    float y0 = fmaf(a0, iv, bt), y1 = fmaf(a1, iv, bt);
    float q0 = fminf(AQ_MAX, fmaxf(0.0f, rintf(y0 / s_out)));
    float q1 = fminf(AQ_MAX, fmaxf(0.0f, rintf(y1 / s_out)));
    if (FINAL) {
      float2 o;
      o.x = q0 * s_out; o.y = q1 * s_out;
      *(float2*)((float*)outv + (size_t)(n * OC + oc) * HW + px0) = o;
    } else {
      uint16_t pk = (uint16_t)((uint32_t)q0 | ((uint32_t)q1 << 8));
      *(uint16_t*)((uint8_t*)outv + (size_t)(n * OC + oc) * HW + px0) = pk;
    }
  }
}

extern "C" void kernel_launch(void* const* d_in, const int* in_sizes, int n_in,
                              void* d_out, int out_size, void* d_ws, size_t ws_size,
                              hipStream_t stream) {
  const float* x    = (const float*)d_in[0];
  const float* w1   = (const float*)d_in[1];
  const float* g1   = (const float*)d_in[2];
  const float* b1   = (const float*)d_in[3];
  const float* m1   = (const float*)d_in[4];
  const float* v1   = (const float*)d_in[5];
  const float* s1   = (const float*)d_in[6];
  const float* wdw1 = (const float*)d_in[7];
  const float* g2   = (const float*)d_in[8];
  const float* b2   = (const float*)d_in[9];
  const float* m2   = (const float*)d_in[10];
  const float* v2   = (const float*)d_in[11];
  const float* s2   = (const float*)d_in[12];
  const float* wpw1 = (const float*)d_in[13];
  const float* g3   = (const float*)d_in[14];
  const float* b3   = (const float*)d_in[15];
  const float* m3   = (const float*)d_in[16];
  const float* v3   = (const float*)d_in[17];
  const float* s3   = (const float*)d_in[18];
  const float* wdw2 = (const float*)d_in[19];
  const float* g4   = (const float*)d_in[20];
  const float* b4   = (const float*)d_in[21];
  const float* m4   = (const float*)d_in[22];
  const float* v4   = (const float*)d_in[23];
  const float* s4   = (const float*)d_in[24];
  const float* wpw2 = (const float*)d_in[25];
  const float* g5   = (const float*)d_in[26];
  const float* b5   = (const float*)d_in[27];
  const float* m5   = (const float*)d_in[28];
  const float* v5   = (const float*)d_in[29];
  const float* s5   = (const float*)d_in[30];

  float* P = (float*)d_ws;
  float* wq2  = P + 864;
  float* wq3  = P + 1152;
  float* wq4  = P + 2688;
  float* wq5  = P + 3120;
  float* inv2 = P + 6256, *beta2 = P + 6288;
  float* inv3 = P + 6320, *beta3 = P + 6368;
  float* inv4 = P + 6416, *beta4 = P + 6464;
  float* inv5 = P + 6512, *beta5 = P + 6576;

  uint8_t* ws8 = (uint8_t*)d_ws;
  uint8_t* x1 = ws8 + 32768;            // [8,32,255,512] codes: 33,423,360 B
  uint8_t* x2 = x1 + 33423360;          // [8,32,128,256]:  8,388,608 B
  uint8_t* x3 = x2 + 8388608;           // [8,48,128,256]: 12,582,912 B
  uint8_t* x4 = ws8 + 32768;            // [8,48,64,128]: aliases x1 (dead)

  prep_all<<<224, 64, 0, stream>>>(w1, g1, b1, m1, v1,
                                   wdw1, g2, b2, m2, v2,
                                   wpw1, g3, b3, m3, v3,
                                   wdw2, g4, b4, m4, v4,
                                   wpw2, g5, b5, m5, v5, P);

  // Stage 1: 8*255*128 groups of 4 px = 261,120 threads
  stage1_kernel<<<1020, 256, 0, stream>>>(x, P, s1, x1);
  // dw1: 32ch, 255x511(512) -> 128x256: 2,097,152 threads
  dw_kernel<32, 255, 511, 512, 128, 256>
      <<<8192, 256, 0, stream>>>(x1, wq2, inv2, beta2, s1, s2, x2);
  // pw1: 32->48 @128x256, 2 px/thread: 131,072 threads
  pw_kernel<32, 48, 32768, false>
      <<<512, 256, 0, stream>>>(x2, wq3, inv3, beta3, s2, s3, x3);
  // dw2: 48ch, 128x256 -> 64x128: 786,432 threads
  dw_kernel<48, 128, 256, 256, 64, 128>
      <<<3072, 256, 0, stream>>>(x3, wq4, inv4, beta4, s3, s4, x4);
  // pw2: 48->64 @64x128 -> fp32 d_out, 2 px/thread: 32,768 threads
  pw_kernel<48, 64, 8192, true>
      <<<128, 256, 0, stream>>>(x4, wq5, inv5, beta5, s4, s5, (float*)d_out);
}